// Round 1
// baseline (100.064 us; speedup 1.0000x reference)
//
#include <hip/hip_runtime.h>

// DeepQNetwork fused forward:  x(B,15) -> onehot(36) -> 128 -> 512 -> 40
// Transposed MFMA scheme (features = M, batch rows = N), v_mfma_f32_16x16x32_bf16:
//   A frag (weights, prepacked fragment-linear in ws): lane = A[m=l16][k=quad*8+j]
//   B frag (activations): lane = act[row=l16][feat=quad*8+j] -> ds_read_b128
//   C/D: lane reg r = D[feat=quad*4+r][row=l16] -> pack 4 feats -> one ds_write_b64
// R8: ZERO barriers, ZERO W2 LDS. R4-R7 showed the barrier-pipelined W2 staging
// phase-locks all waves into the same pipe phase -> elapsed ~= SUM of pipe busy
// (MFMA+DS+VALU ~= 31us, matches R6's 34) instead of MAX (~12.4us MFMA floor).
// Fix = hipBLASLt-style register software pipeline: W2 frag-quads double-buffered
// in VGPRs via plain global loads issued one mtl-step (16 MFMAs ~= 310 cyc) ahead;
// no waitcnt-before-barrier drains; 8 free-drifting waves/CU co-schedule
// MFMA/DS/VMEM/VALU pipes. DS pipe now carries activations only.
// 2-wave blocks (64 rows/wave), grid 1024, LDS 18432B -> 4 blocks/CU.
// R9: identical resubmission — round 0 bench failed at container acquisition
// (no compile/verify/counter signal); re-establishing baseline + rocprof anchor.

typedef short bf16x8 __attribute__((ext_vector_type(8)));
typedef float f32x4 __attribute__((ext_vector_type(4)));
typedef unsigned int u32;

#define NW1F 8192              // 16 frags  (8 mt * 2 ks)
#define NW2F 65536             // 128 frags (32 mt * 4 ks)
#define NW4F 24576             // 48 frags  (3 mt * 16 ks)
#define PACK_TOTAL (NW1F + NW2F + NW4F)   // 98304 shorts = 192 KB of ws
#define PACK_THREADS (PACK_TOTAL / 8)     // one b128 store per thread

__device__ __forceinline__ unsigned short f2bf(float f) {
  union { float f; unsigned u; } a; a.f = f;
  unsigned r = a.u + 0x7fffu + ((a.u >> 16) & 1u);
  return (unsigned short)(r >> 16);
}
// gfx950 packed convert, RNE: two f32 -> bf16x2 in one VALU op.
__device__ __forceinline__ u32 cvtpk(float lo, float hi) {
  u32 r;
  asm("v_cvt_pk_bf16_f32 %0, %1, %2" : "=v"(r) : "v"(lo), "v"(hi));
  return r;
}

// Prepack W1^T (128x64, K-pad 36->64), W2^T (512x128), W4^T (48x512, M-pad 40->48)
// as A-fragment-linear bf16: frag*512 + lane*8 + j = A[m=mt*16+l16][k=ks*32+quad*8+j].
__global__ void pack_weights(const float* __restrict__ W1,
                             const float* __restrict__ W2,
                             const float* __restrict__ W4,
                             unsigned short* __restrict__ wf) {
  int t = blockIdx.x * 256 + threadIdx.x;
  if (t >= PACK_THREADS) return;
  int fid = t >> 6, lane = t & 63;
  int l16 = lane & 15, quad = lane >> 4;
  float vals[8];
  if (fid < 16) {                       // W1: fid = mt*2+ks
    int mt = fid >> 1, ks = fid & 1;
    int m = mt * 16 + l16, k0 = ks * 32 + quad * 8;
#pragma unroll
    for (int j = 0; j < 8; ++j) { int k = k0 + j; vals[j] = (k < 36) ? W1[k * 128 + m] : 0.f; }
  } else if (fid < 144) {               // W2: fid-16 = mt*4+ks
    int f = fid - 16, mt = f >> 2, ks = f & 3;
    int m = mt * 16 + l16, k0 = ks * 32 + quad * 8;
#pragma unroll
    for (int j = 0; j < 8; ++j) vals[j] = W2[(k0 + j) * 512 + m];
  } else {                              // W4: fid-144 = mt*16+ks
    int f = fid - 144, mt = f >> 4, ks = f & 15;
    int m = mt * 16 + l16, k0 = ks * 32 + quad * 8;
#pragma unroll
    for (int j = 0; j < 8; ++j) vals[j] = (m < 40) ? W4[(k0 + j) * 40 + m] : 0.f;
  }
  u32 p[4];
#pragma unroll
  for (int j = 0; j < 4; ++j) p[j] = cvtpk(vals[2 * j], vals[2 * j + 1]);
  *(bf16x8*)(wf + (size_t)t * 8) = *(bf16x8*)p;
}

// 128 threads = 2 waves; each wave privately owns 64 rows (4 N-groups of 16).
// All LDS traffic is wave-private (DS ops complete in order per wave) -> the
// kernel contains NO __syncthreads / s_barrier at all.
__global__ __launch_bounds__(128, 2) void dqn_fused(
    const float* __restrict__ x,
    const unsigned short* __restrict__ wf,
    const float* __restrict__ b1,
    const float* __restrict__ b2,
    const float* __restrict__ b4,
    float* __restrict__ out) {
  __shared__ __align__(16) unsigned short sBuf[2 * 64 * 72];  // 18432 B -> 4 blocks/CU

  const int tid  = threadIdx.x;
  const int lane = tid & 63;
  const int wave = tid >> 6;                     // 0 or 1
  const int quad = lane >> 4;
  const int l16  = lane & 15;
  const int row0 = blockIdx.x << 7;              // 128 rows per block
  const int lr0  = wave * 64;
  unsigned short* su = sBuf + wave * (64 * 72);  // wave-private

  const unsigned short* w2f = wf + NW1F;
  const unsigned short* w4f = wf + NW1F + NW2F;
  const unsigned short* w2p = w2f + lane * 8;    // frag f lives at w2p + f*512

  // software-pipeline prologue: W2 frag-quad 0 (chunk0, mtl0) into registers now;
  // its latency overlaps input staging + the whole L1 GEMM.
  bf16x8 curW[4];
#pragma unroll
  for (int k = 0; k < 4; ++k) curW[k] = *(const bf16x8*)(w2p + (size_t)k * 512);

  // ---- stage 1: one-hot input rows in LDS (bf16), K padded 36->64; 1 row/lane ----
  {
    const float* xr = x + (size_t)(row0 + lr0 + lane) * 15;
    unsigned short* dst = su + lane * 72;
    bf16x8 z = {0, 0, 0, 0, 0, 0, 0, 0};
#pragma unroll
    for (int c = 8; c < 64; c += 8) *(bf16x8*)(dst + c) = z;   // zero cols 8..63
    u32 p[4];
#pragma unroll
    for (int i = 0; i < 4; ++i) p[i] = cvtpk(xr[2 * i], xr[2 * i + 1]);
    *(bf16x8*)dst = *(bf16x8*)p;                 // keep cols 0..7
    *(u32*)(dst + 8) = cvtpk(xr[8], xr[9]);      // keep cols 8..9
    dst[10] = f2bf(xr[10]);                      // keep col 10
    int hold = (int)xr[11]; hold = hold < 0 ? 0 : (hold > 3 ? 3 : hold);
    dst[11 + hold] = 0x3F80;                     // bf16 1.0
#pragma unroll
    for (int t = 0; t < 3; ++t) {
      int nx = (int)xr[12 + t] - 1; nx = nx < 0 ? 0 : (nx > 6 ? 6 : nx);
      dst[15 + t * 7 + nx] = 0x3F80;
    }
  }

  const f32x4 vzero = {0.f, 0.f, 0.f, 0.f};

  // ---- stage 2: h1^T = relu(W1^T @ inp^T + b1), two mt-halves; af1 frags to regs.
  bf16x8 ib[4][2];
#pragma unroll
  for (int rg = 0; rg < 4; ++rg)
#pragma unroll
    for (int ks = 0; ks < 2; ++ks)
      ib[rg][ks] = *(const bf16x8*)(su + (rg * 16 + l16) * 72 + ks * 32 + quad * 8);

  bf16x8 af1[4][4];   // [rg][ks_out]: h1 B-frags, filled per half
#pragma unroll
  for (int half = 0; half < 2; ++half) {
    // hoist this half's 8 W1 frags before the MFMA burst (latency overlap)
    bf16x8 wa[4][2];
#pragma unroll
    for (int mtl = 0; mtl < 4; ++mtl)
#pragma unroll
      for (int ks = 0; ks < 2; ++ks)
        wa[mtl][ks] = *(const bf16x8*)(
            wf + (size_t)(((half * 4 + mtl) * 2 + ks) * 64 + lane) * 8);

    f32x4 acc1[4][4];   // [mtl][rg]
#pragma unroll
    for (int mtl = 0; mtl < 4; ++mtl)
#pragma unroll
      for (int rg = 0; rg < 4; ++rg) acc1[mtl][rg] = vzero;

#pragma unroll
    for (int mtl = 0; mtl < 4; ++mtl)
#pragma unroll
      for (int ks = 0; ks < 2; ++ks)
#pragma unroll
        for (int rg = 0; rg < 4; ++rg)
          acc1[mtl][rg] = __builtin_amdgcn_mfma_f32_16x16x32_bf16(wa[mtl][ks], ib[rg][ks], acc1[mtl][rg], 0, 0, 0);

#pragma unroll
    for (int mtl = 0; mtl < 4; ++mtl) {
      f32x4 bias = *(const f32x4*)(b1 + (half * 4 + mtl) * 16 + quad * 4);
#pragma unroll
      for (int rg = 0; rg < 4; ++rg) {
        float v0 = fmaxf(acc1[mtl][rg][0] + bias[0], 0.f);
        float v1 = fmaxf(acc1[mtl][rg][1] + bias[1], 0.f);
        float v2 = fmaxf(acc1[mtl][rg][2] + bias[2], 0.f);
        float v3 = fmaxf(acc1[mtl][rg][3] + bias[3], 0.f);
        uint2 pk = {cvtpk(v0, v1), cvtpk(v2, v3)};
        *(uint2*)(su + (rg * 16 + l16) * 72 + mtl * 16 + quad * 4) = pk;
      }
    }
#pragma unroll
    for (int rg = 0; rg < 4; ++rg)
#pragma unroll
      for (int ksl = 0; ksl < 2; ++ksl)
        af1[rg][half * 2 + ksl] =
            *(const bf16x8*)(su + (rg * 16 + l16) * 72 + ksl * 32 + quad * 8);
  }

  f32x4 accO[3][4];
#pragma unroll
  for (int mt = 0; mt < 3; ++mt)
#pragma unroll
    for (int rg = 0; rg < 4; ++rg) accO[mt][rg] = vzero;

  // ---- stage 3: register-pipelined W2 K-loop, no barriers ----
  // frag-quad f covers (chunk,mtl) = (f/16, (f%16)/4); 32 quads total.
  for (int chunk = 0; chunk < 8; ++chunk) {
    // W4 frags for this chunk: issued at chunk start, used after 64 MFMAs
    bf16x8 w4r[2][3];
#pragma unroll
    for (int ks3 = 0; ks3 < 2; ++ks3)
#pragma unroll
      for (int mt3 = 0; mt3 < 3; ++mt3)
        w4r[ks3][mt3] = *(const bf16x8*)(
            w4f + (size_t)((mt3 * 16 + chunk * 2 + ks3) * 64 + lane) * 8);

#pragma unroll
    for (int mtl = 0; mtl < 4; ++mtl) {
      // prefetch next frag-quad (one full mtl-step = 16 MFMAs ahead)
      int fb = chunk * 16 + mtl * 4 + 4;
      if (fb >= 128) fb = 0;             // harmless redundant load on last step
      bf16x8 nxtW[4];
#pragma unroll
      for (int k = 0; k < 4; ++k)
        nxtW[k] = *(const bf16x8*)(w2p + (size_t)(fb + k) * 512);

      f32x4 acc2[4];                     // [rg]
#pragma unroll
      for (int rg = 0; rg < 4; ++rg) acc2[rg] = vzero;
#pragma unroll
      for (int ks = 0; ks < 4; ++ks)
#pragma unroll
        for (int rg = 0; rg < 4; ++rg)
          acc2[rg] = __builtin_amdgcn_mfma_f32_16x16x32_bf16(curW[ks], af1[rg][ks], acc2[rg], 0, 0, 0);

      // bias+relu -> h2 cols mtl*16 + quad*4, wave-private b64 writes
      f32x4 bias = *(const f32x4*)(b2 + chunk * 64 + mtl * 16 + quad * 4);
#pragma unroll
      for (int rg = 0; rg < 4; ++rg) {
        float v0 = fmaxf(acc2[rg][0] + bias[0], 0.f);
        float v1 = fmaxf(acc2[rg][1] + bias[1], 0.f);
        float v2 = fmaxf(acc2[rg][2] + bias[2], 0.f);
        float v3 = fmaxf(acc2[rg][3] + bias[3], 0.f);
        uint2 pk = {cvtpk(v0, v1), cvtpk(v2, v3)};
        *(uint2*)(su + (rg * 16 + l16) * 72 + mtl * 16 + quad * 4) = pk;
      }
#pragma unroll
      for (int k = 0; k < 4; ++k) curW[k] = nxtW[k];
    }

    // L3 partial on this chunk's 64 feats (h2 wave-private; W4 from registers)
#pragma unroll
    for (int ks3 = 0; ks3 < 2; ++ks3) {
      bf16x8 h[4];
#pragma unroll
      for (int rg = 0; rg < 4; ++rg)
        h[rg] = *(const bf16x8*)(su + (rg * 16 + l16) * 72 + ks3 * 32 + quad * 8);
#pragma unroll
      for (int mt3 = 0; mt3 < 3; ++mt3)
#pragma unroll
        for (int rg = 0; rg < 4; ++rg)
          accO[mt3][rg] = __builtin_amdgcn_mfma_f32_16x16x32_bf16(w4r[ks3][mt3], h[rg], accO[mt3][rg], 0, 0, 0);
    }
  }

  // ---- epilogue: +b4, float4 stores (lane holds 4 consecutive out-cols) ----
#pragma unroll
  for (int mt3 = 0; mt3 < 3; ++mt3) {
    int colbase = mt3 * 16 + quad * 4;
    if (colbase < 40) {                      // drops pad cols 40..47
      f32x4 bias = *(const f32x4*)(b4 + colbase);
#pragma unroll
      for (int rg = 0; rg < 4; ++rg) {
        f32x4 v = accO[mt3][rg] + bias;
        size_t row = (size_t)(row0 + lr0 + rg * 16 + l16);
        *(f32x4*)(out + row * 40 + colbase) = v;
      }
    }
  }
}

extern "C" void kernel_launch(void* const* d_in, const int* in_sizes, int n_in,
                              void* d_out, int out_size, void* d_ws, size_t ws_size,
                              hipStream_t stream) {
  const float* x  = (const float*)d_in[0];
  const float* W1 = (const float*)d_in[1];
  const float* b1 = (const float*)d_in[2];
  const float* W2 = (const float*)d_in[3];
  const float* b2 = (const float*)d_in[4];
  const float* W4 = (const float*)d_in[5];
  const float* b4 = (const float*)d_in[6];
  float* out = (float*)d_out;
  unsigned short* wf = (unsigned short*)d_ws;   // 192 KB of ws

  int B = in_sizes[0] / 15;

  hipLaunchKernelGGL(pack_weights, dim3((PACK_THREADS + 255) / 256), dim3(256), 0, stream,
                     W1, W2, W4, wf);
  hipLaunchKernelGGL(dqn_fused, dim3(B / 128), dim3(128), 0, stream,
                     x, wf, b1, b2, b4, out);
}

// Round 2
// 97.521 us; speedup vs baseline: 1.0261x; 1.0261x over previous
//
#include <hip/hip_runtime.h>

// DeepQNetwork fused forward:  x(B,15) -> onehot(36) -> 128 -> 512 -> 40
// Transposed MFMA scheme (features = M, batch rows = N), v_mfma_f32_16x16x32_bf16:
//   A frag (weights, prepacked fragment-linear in ws): lane = A[m=l16][k=quad*8+j]
//   B frag (activations): lane = act[row=l16][feat=quad*8+j] -> ds_read_b128
//   C/D: lane reg r = D[feat=quad*4+r][row=l16] -> pack 4 feats -> one ds_write_b64
// R8: ZERO barriers, ZERO W2 LDS (register software pipeline for W2).
// R10: timed region decomposition (R9 profile): ws-poison fill 41.6us is
// harness-fixed; dqn_fused deduced ~35-42us vs 12.4us MFMA floor -> pipes still
// near-serialized. Two mechanical serializers removed:
//   (1) curW<-nxtW register rotation (512 v_movs/wave + per-mtl vmcnt drain)
//       -> parity double-buffer W[mtl&1], prefetch into W[(mtl+1)&1]; no copies.
//   (2) stage-3 bias adds (512 v_add/wave) -> acc2 initialized with b2 (MFMA C
//       operand carries bias); epilogue is fmax+cvtpk only.
// Plus: s_setprio(1/0) around MFMA bursts (2 drifting waves/SIMD = T5 regime),
// w4r loads moved into ks3 loop (-12 VGPR).
// 2-wave blocks (64 rows/wave), grid 1024, LDS 18432B -> 4 blocks/CU.

typedef short bf16x8 __attribute__((ext_vector_type(8)));
typedef float f32x4 __attribute__((ext_vector_type(4)));
typedef unsigned int u32;

#define NW1F 8192              // 16 frags  (8 mt * 2 ks)
#define NW2F 65536             // 128 frags (32 mt * 4 ks)
#define NW4F 24576             // 48 frags  (3 mt * 16 ks)
#define PACK_TOTAL (NW1F + NW2F + NW4F)   // 98304 shorts = 192 KB of ws
#define PACK_THREADS (PACK_TOTAL / 8)     // one b128 store per thread

__device__ __forceinline__ unsigned short f2bf(float f) {
  union { float f; unsigned u; } a; a.f = f;
  unsigned r = a.u + 0x7fffu + ((a.u >> 16) & 1u);
  return (unsigned short)(r >> 16);
}
// gfx950 packed convert, RNE: two f32 -> bf16x2 in one VALU op.
__device__ __forceinline__ u32 cvtpk(float lo, float hi) {
  u32 r;
  asm("v_cvt_pk_bf16_f32 %0, %1, %2" : "=v"(r) : "v"(lo), "v"(hi));
  return r;
}

// Prepack W1^T (128x64, K-pad 36->64), W2^T (512x128), W4^T (48x512, M-pad 40->48)
// as A-fragment-linear bf16: frag*512 + lane*8 + j = A[m=mt*16+l16][k=ks*32+quad*8+j].
__global__ void pack_weights(const float* __restrict__ W1,
                             const float* __restrict__ W2,
                             const float* __restrict__ W4,
                             unsigned short* __restrict__ wf) {
  int t = blockIdx.x * 256 + threadIdx.x;
  if (t >= PACK_THREADS) return;
  int fid = t >> 6, lane = t & 63;
  int l16 = lane & 15, quad = lane >> 4;
  float vals[8];
  if (fid < 16) {                       // W1: fid = mt*2+ks
    int mt = fid >> 1, ks = fid & 1;
    int m = mt * 16 + l16, k0 = ks * 32 + quad * 8;
#pragma unroll
    for (int j = 0; j < 8; ++j) { int k = k0 + j; vals[j] = (k < 36) ? W1[k * 128 + m] : 0.f; }
  } else if (fid < 144) {               // W2: fid-16 = mt*4+ks
    int f = fid - 16, mt = f >> 2, ks = f & 3;
    int m = mt * 16 + l16, k0 = ks * 32 + quad * 8;
#pragma unroll
    for (int j = 0; j < 8; ++j) vals[j] = W2[(k0 + j) * 512 + m];
  } else {                              // W4: fid-144 = mt*16+ks
    int f = fid - 144, mt = f >> 4, ks = f & 15;
    int m = mt * 16 + l16, k0 = ks * 32 + quad * 8;
#pragma unroll
    for (int j = 0; j < 8; ++j) vals[j] = (m < 40) ? W4[(k0 + j) * 40 + m] : 0.f;
  }
  u32 p[4];
#pragma unroll
  for (int j = 0; j < 4; ++j) p[j] = cvtpk(vals[2 * j], vals[2 * j + 1]);
  *(bf16x8*)(wf + (size_t)t * 8) = *(bf16x8*)p;
}

// 128 threads = 2 waves; each wave privately owns 64 rows (4 N-groups of 16).
// All LDS traffic is wave-private (DS ops complete in order per wave) -> the
// kernel contains NO __syncthreads / s_barrier at all.
__global__ __launch_bounds__(128, 2) void dqn_fused(
    const float* __restrict__ x,
    const unsigned short* __restrict__ wf,
    const float* __restrict__ b1,
    const float* __restrict__ b2,
    const float* __restrict__ b4,
    float* __restrict__ out) {
  __shared__ __align__(16) unsigned short sBuf[2 * 64 * 72];  // 18432 B -> 4 blocks/CU

  const int tid  = threadIdx.x;
  const int lane = tid & 63;
  const int wave = tid >> 6;                     // 0 or 1
  const int quad = lane >> 4;
  const int l16  = lane & 15;
  const int row0 = blockIdx.x << 7;              // 128 rows per block
  const int lr0  = wave * 64;
  unsigned short* su = sBuf + wave * (64 * 72);  // wave-private

  const unsigned short* w2f = wf + NW1F;
  const unsigned short* w4f = wf + NW1F + NW2F;
  const unsigned short* w2p = w2f + lane * 8;    // frag f lives at w2p + f*512

  // software-pipeline prologue: W2 frag-quad 0 (chunk0, mtl0) into parity buffer 0;
  // its latency overlaps input staging + the whole L1 GEMM.
  bf16x8 W[2][4];
#pragma unroll
  for (int k = 0; k < 4; ++k) W[0][k] = *(const bf16x8*)(w2p + (size_t)k * 512);

  // ---- stage 1: one-hot input rows in LDS (bf16), K padded 36->64; 1 row/lane ----
  {
    const float* xr = x + (size_t)(row0 + lr0 + lane) * 15;
    unsigned short* dst = su + lane * 72;
    bf16x8 z = {0, 0, 0, 0, 0, 0, 0, 0};
#pragma unroll
    for (int c = 8; c < 64; c += 8) *(bf16x8*)(dst + c) = z;   // zero cols 8..63
    u32 p[4];
#pragma unroll
    for (int i = 0; i < 4; ++i) p[i] = cvtpk(xr[2 * i], xr[2 * i + 1]);
    *(bf16x8*)dst = *(bf16x8*)p;                 // keep cols 0..7
    *(u32*)(dst + 8) = cvtpk(xr[8], xr[9]);      // keep cols 8..9
    dst[10] = f2bf(xr[10]);                      // keep col 10
    int hold = (int)xr[11]; hold = hold < 0 ? 0 : (hold > 3 ? 3 : hold);
    dst[11 + hold] = 0x3F80;                     // bf16 1.0
#pragma unroll
    for (int t = 0; t < 3; ++t) {
      int nx = (int)xr[12 + t] - 1; nx = nx < 0 ? 0 : (nx > 6 ? 6 : nx);
      dst[15 + t * 7 + nx] = 0x3F80;
    }
  }

  const f32x4 vzero = {0.f, 0.f, 0.f, 0.f};

  // ---- stage 2: h1^T = relu(W1^T @ inp^T + b1), two mt-halves; af1 frags to regs.
  bf16x8 ib[4][2];
#pragma unroll
  for (int rg = 0; rg < 4; ++rg)
#pragma unroll
    for (int ks = 0; ks < 2; ++ks)
      ib[rg][ks] = *(const bf16x8*)(su + (rg * 16 + l16) * 72 + ks * 32 + quad * 8);

  bf16x8 af1[4][4];   // [rg][ks_out]: h1 B-frags, filled per half
#pragma unroll
  for (int half = 0; half < 2; ++half) {
    // hoist this half's 8 W1 frags before the MFMA burst (latency overlap)
    bf16x8 wa[4][2];
#pragma unroll
    for (int mtl = 0; mtl < 4; ++mtl)
#pragma unroll
      for (int ks = 0; ks < 2; ++ks)
        wa[mtl][ks] = *(const bf16x8*)(
            wf + (size_t)(((half * 4 + mtl) * 2 + ks) * 64 + lane) * 8);

    f32x4 acc1[4][4];   // [mtl][rg]
#pragma unroll
    for (int mtl = 0; mtl < 4; ++mtl)
#pragma unroll
      for (int rg = 0; rg < 4; ++rg) acc1[mtl][rg] = vzero;

    __builtin_amdgcn_s_setprio(1);
#pragma unroll
    for (int mtl = 0; mtl < 4; ++mtl)
#pragma unroll
      for (int ks = 0; ks < 2; ++ks)
#pragma unroll
        for (int rg = 0; rg < 4; ++rg)
          acc1[mtl][rg] = __builtin_amdgcn_mfma_f32_16x16x32_bf16(wa[mtl][ks], ib[rg][ks], acc1[mtl][rg], 0, 0, 0);
    __builtin_amdgcn_s_setprio(0);

#pragma unroll
    for (int mtl = 0; mtl < 4; ++mtl) {
      f32x4 bias = *(const f32x4*)(b1 + (half * 4 + mtl) * 16 + quad * 4);
#pragma unroll
      for (int rg = 0; rg < 4; ++rg) {
        float v0 = fmaxf(acc1[mtl][rg][0] + bias[0], 0.f);
        float v1 = fmaxf(acc1[mtl][rg][1] + bias[1], 0.f);
        float v2 = fmaxf(acc1[mtl][rg][2] + bias[2], 0.f);
        float v3 = fmaxf(acc1[mtl][rg][3] + bias[3], 0.f);
        uint2 pk = {cvtpk(v0, v1), cvtpk(v2, v3)};
        *(uint2*)(su + (rg * 16 + l16) * 72 + mtl * 16 + quad * 4) = pk;
      }
    }
#pragma unroll
    for (int rg = 0; rg < 4; ++rg)
#pragma unroll
      for (int ksl = 0; ksl < 2; ++ksl)
        af1[rg][half * 2 + ksl] =
            *(const bf16x8*)(su + (rg * 16 + l16) * 72 + ksl * 32 + quad * 8);
  }

  f32x4 accO[3][4];
#pragma unroll
  for (int mt = 0; mt < 3; ++mt)
#pragma unroll
    for (int rg = 0; rg < 4; ++rg) accO[mt][rg] = vzero;

  // ---- stage 3: register-pipelined W2 K-loop, no barriers, no reg rotation ----
  // frag-quad f covers (chunk,mtl) = (f/16, (f%16)/4); 32 quads total.
  // Parity: mtl uses W[mtl&1], prefetches W[(mtl+1)&1]; 4 steps/chunk (even)
  // makes the pattern chunk-invariant -> rolled chunk loop, zero copies.
  for (int chunk = 0; chunk < 8; ++chunk) {
    // this chunk's b2 slice (L1-hot after chunk 0); feeds acc2 init below
    f32x4 bias2[4];
#pragma unroll
    for (int mtl = 0; mtl < 4; ++mtl)
      bias2[mtl] = *(const f32x4*)(b2 + chunk * 64 + mtl * 16 + quad * 4);

#pragma unroll
    for (int mtl = 0; mtl < 4; ++mtl) {
      // prefetch next frag-quad (one full mtl-step = 16 MFMAs ahead)
      int fb = chunk * 16 + mtl * 4 + 4;
      if (fb >= 128) fb = 0;             // harmless redundant load on last step
#pragma unroll
      for (int k = 0; k < 4; ++k)
        W[(mtl + 1) & 1][k] = *(const bf16x8*)(w2p + (size_t)(fb + k) * 512);

      f32x4 acc2[4];                     // [rg], bias carried in C operand
#pragma unroll
      for (int rg = 0; rg < 4; ++rg) acc2[rg] = bias2[mtl];

      __builtin_amdgcn_s_setprio(1);
#pragma unroll
      for (int ks = 0; ks < 4; ++ks)
#pragma unroll
        for (int rg = 0; rg < 4; ++rg)
          acc2[rg] = __builtin_amdgcn_mfma_f32_16x16x32_bf16(W[mtl & 1][ks], af1[rg][ks], acc2[rg], 0, 0, 0);
      __builtin_amdgcn_s_setprio(0);

      // relu -> h2 cols mtl*16 + quad*4, wave-private b64 writes
#pragma unroll
      for (int rg = 0; rg < 4; ++rg) {
        float v0 = fmaxf(acc2[rg][0], 0.f);
        float v1 = fmaxf(acc2[rg][1], 0.f);
        float v2 = fmaxf(acc2[rg][2], 0.f);
        float v3 = fmaxf(acc2[rg][3], 0.f);
        uint2 pk = {cvtpk(v0, v1), cvtpk(v2, v3)};
        *(uint2*)(su + (rg * 16 + l16) * 72 + mtl * 16 + quad * 4) = pk;
      }
    }

    // L3 partial on this chunk's 64 feats (h2 wave-private; W4 loads per ks3)
#pragma unroll
    for (int ks3 = 0; ks3 < 2; ++ks3) {
      bf16x8 w4r[3];
#pragma unroll
      for (int mt3 = 0; mt3 < 3; ++mt3)
        w4r[mt3] = *(const bf16x8*)(
            w4f + (size_t)((mt3 * 16 + chunk * 2 + ks3) * 64 + lane) * 8);
      bf16x8 h[4];
#pragma unroll
      for (int rg = 0; rg < 4; ++rg)
        h[rg] = *(const bf16x8*)(su + (rg * 16 + l16) * 72 + ks3 * 32 + quad * 8);
      __builtin_amdgcn_s_setprio(1);
#pragma unroll
      for (int mt3 = 0; mt3 < 3; ++mt3)
#pragma unroll
        for (int rg = 0; rg < 4; ++rg)
          accO[mt3][rg] = __builtin_amdgcn_mfma_f32_16x16x32_bf16(w4r[mt3], h[rg], accO[mt3][rg], 0, 0, 0);
      __builtin_amdgcn_s_setprio(0);
    }
  }

  // ---- epilogue: +b4, float4 stores (lane holds 4 consecutive out-cols) ----
#pragma unroll
  for (int mt3 = 0; mt3 < 3; ++mt3) {
    int colbase = mt3 * 16 + quad * 4;
    if (colbase < 40) {                      // drops pad cols 40..47 (b4 OOB-safe)
      f32x4 bias = *(const f32x4*)(b4 + colbase);
#pragma unroll
      for (int rg = 0; rg < 4; ++rg) {
        f32x4 v = accO[mt3][rg] + bias;
        size_t row = (size_t)(row0 + lr0 + rg * 16 + l16);
        *(f32x4*)(out + row * 40 + colbase) = v;
      }
    }
  }
}

extern "C" void kernel_launch(void* const* d_in, const int* in_sizes, int n_in,
                              void* d_out, int out_size, void* d_ws, size_t ws_size,
                              hipStream_t stream) {
  const float* x  = (const float*)d_in[0];
  const float* W1 = (const float*)d_in[1];
  const float* b1 = (const float*)d_in[2];
  const float* W2 = (const float*)d_in[3];
  const float* b2 = (const float*)d_in[4];
  const float* W4 = (const float*)d_in[5];
  const float* b4 = (const float*)d_in[6];
  float* out = (float*)d_out;
  unsigned short* wf = (unsigned short*)d_ws;   // 192 KB of ws

  int B = in_sizes[0] / 15;

  hipLaunchKernelGGL(pack_weights, dim3((PACK_THREADS + 255) / 256), dim3(256), 0, stream,
                     W1, W2, W4, wf);
  hipLaunchKernelGGL(dqn_fused, dim3(B / 128), dim3(128), 0, stream,
                     x, wf, b1, b2, b4, out);
}

// Round 3
// 96.616 us; speedup vs baseline: 1.0357x; 1.0094x over previous
//
#include <hip/hip_runtime.h>

// DeepQNetwork fused forward:  x(B,15) -> onehot(36) -> 128 -> 512 -> 40
// Transposed MFMA scheme (features = M, batch rows = N), v_mfma_f32_16x16x32_bf16:
//   A frag (weights, prepacked fragment-linear in ws): lane = A[m=l16][k=quad*8+j]
//   B frag (activations): lane = act[row=l16][feat=quad*8+j] -> ds_read_b128
//   C/D: lane reg r = D[feat=quad*4+r][row=l16] -> pack 4 feats -> one ds_write_b64
// R8: ZERO barriers, ZERO W2 LDS (register software pipeline for W2).
// R10 (-2.5us): parity W dbuf (no reg rotation), stage-3 bias via MFMA C operand,
// setprio around bursts.
// R11: chunk-level software pipeline for stage 3. Theory: per-SIMD MFMA demand
// 29.8k cyc vs ~84k elapsed (35% duty) -> both waves idle the matrix pipe at
// chunk ends, where L3's ds_reads wait on all 4 epilogues' writes and W4 loads
// (R10 moved them next to use - regression) expose L2 latency. Fix:
//   (1) h2 double-buffered in LDS (row stride 72->136; buf0 = dead input cols
//       0..63, buf1 = cols 72..135) -> chunk c's mtl bursts independent of
//       chunk c-1's L3.
//   (2) L3 partial of chunk c-1 interleaved INSIDE chunk c's mtl loop (h reads
//       one mtl-step ahead; L3 MFMA bursts after mtl1/mtl3 epilogues).
//   (3) W4 loads re-hoisted ~1.5 mtl-steps ahead of use (w4a/w4b split).
//   (4) stage-2 bias through MFMA C operand (-128 VALU/wave).
// 2-wave blocks (64 rows/wave), grid 1024, LDS 34816B -> 4 blocks/CU.

typedef short bf16x8 __attribute__((ext_vector_type(8)));
typedef float f32x4 __attribute__((ext_vector_type(4)));
typedef unsigned int u32;

#define NW1F 8192              // 16 frags  (8 mt * 2 ks)
#define NW2F 65536             // 128 frags (32 mt * 4 ks)
#define NW4F 24576             // 48 frags  (3 mt * 16 ks)
#define PACK_TOTAL (NW1F + NW2F + NW4F)   // 98304 shorts = 192 KB of ws
#define PACK_THREADS (PACK_TOTAL / 8)     // one b128 store per thread

#define SROW 136               // LDS row stride in shorts (h1 0..63 | pad | h2b 72..135)

__device__ __forceinline__ unsigned short f2bf(float f) {
  union { float f; unsigned u; } a; a.f = f;
  unsigned r = a.u + 0x7fffu + ((a.u >> 16) & 1u);
  return (unsigned short)(r >> 16);
}
// gfx950 packed convert, RNE: two f32 -> bf16x2 in one VALU op.
__device__ __forceinline__ u32 cvtpk(float lo, float hi) {
  u32 r;
  asm("v_cvt_pk_bf16_f32 %0, %1, %2" : "=v"(r) : "v"(lo), "v"(hi));
  return r;
}

// Prepack W1^T (128x64, K-pad 36->64), W2^T (512x128), W4^T (48x512, M-pad 40->48)
// as A-fragment-linear bf16: frag*512 + lane*8 + j = A[m=mt*16+l16][k=ks*32+quad*8+j].
__global__ void pack_weights(const float* __restrict__ W1,
                             const float* __restrict__ W2,
                             const float* __restrict__ W4,
                             unsigned short* __restrict__ wf) {
  int t = blockIdx.x * 256 + threadIdx.x;
  if (t >= PACK_THREADS) return;
  int fid = t >> 6, lane = t & 63;
  int l16 = lane & 15, quad = lane >> 4;
  float vals[8];
  if (fid < 16) {                       // W1: fid = mt*2+ks
    int mt = fid >> 1, ks = fid & 1;
    int m = mt * 16 + l16, k0 = ks * 32 + quad * 8;
#pragma unroll
    for (int j = 0; j < 8; ++j) { int k = k0 + j; vals[j] = (k < 36) ? W1[k * 128 + m] : 0.f; }
  } else if (fid < 144) {               // W2: fid-16 = mt*4+ks
    int f = fid - 16, mt = f >> 2, ks = f & 3;
    int m = mt * 16 + l16, k0 = ks * 32 + quad * 8;
#pragma unroll
    for (int j = 0; j < 8; ++j) vals[j] = W2[(k0 + j) * 512 + m];
  } else {                              // W4: fid-144 = mt*16+ks
    int f = fid - 144, mt = f >> 4, ks = f & 15;
    int m = mt * 16 + l16, k0 = ks * 32 + quad * 8;
#pragma unroll
    for (int j = 0; j < 8; ++j) vals[j] = (m < 40) ? W4[(k0 + j) * 40 + m] : 0.f;
  }
  u32 p[4];
#pragma unroll
  for (int j = 0; j < 4; ++j) p[j] = cvtpk(vals[2 * j], vals[2 * j + 1]);
  *(bf16x8*)(wf + (size_t)t * 8) = *(bf16x8*)p;
}

// ---- stage-3 building-block macros (literal args only -> all reg indices fold) ----
// One W2 mtl-step of `chunk`: prefetch next W frag-quad, 16 MFMAs, relu+pack to
// h2 buffer at column offset hb.
#define MTL_STEP(chunk, mtl, hb)                                               \
  {                                                                            \
    int fb = (chunk) * 16 + (mtl) * 4 + 4;                                     \
    if (fb >= 128) fb = 0; /* harmless redundant load on last step */          \
    _Pragma("unroll")                                                          \
    for (int k = 0; k < 4; ++k)                                                \
      W[((mtl) + 1) & 1][k] = *(const bf16x8*)(w2p + (size_t)(fb + k) * 512);  \
    f32x4 acc2[4];                                                             \
    _Pragma("unroll")                                                          \
    for (int rg = 0; rg < 4; ++rg) acc2[rg] = bias2[mtl];                      \
    __builtin_amdgcn_s_setprio(1);                                             \
    _Pragma("unroll")                                                          \
    for (int ks = 0; ks < 4; ++ks)                                             \
      _Pragma("unroll")                                                        \
      for (int rg = 0; rg < 4; ++rg)                                           \
        acc2[rg] = __builtin_amdgcn_mfma_f32_16x16x32_bf16(                    \
            W[(mtl) & 1][ks], af1[rg][ks], acc2[rg], 0, 0, 0);                 \
    __builtin_amdgcn_s_setprio(0);                                             \
    _Pragma("unroll")                                                          \
    for (int rg = 0; rg < 4; ++rg) {                                           \
      float v0 = fmaxf(acc2[rg][0], 0.f);                                      \
      float v1 = fmaxf(acc2[rg][1], 0.f);                                      \
      float v2 = fmaxf(acc2[rg][2], 0.f);                                      \
      float v3 = fmaxf(acc2[rg][3], 0.f);                                      \
      uint2 pk = {cvtpk(v0, v1), cvtpk(v2, v3)};                               \
      *(uint2*)(su + (rg * 16 + l16) * SROW + (hb) + (mtl) * 16 + quad * 4) = pk; \
    }                                                                          \
  }

#define H_READ(dst, hbp, ks3)                                                  \
  _Pragma("unroll")                                                            \
  for (int rg = 0; rg < 4; ++rg)                                               \
    dst[rg] = *(const bf16x8*)(su + (rg * 16 + l16) * SROW + (hbp) + (ks3) * 32 + quad * 8);

#define W4_LOAD(dst, chunkprev, ks3)                                           \
  _Pragma("unroll")                                                            \
  for (int mt3 = 0; mt3 < 3; ++mt3)                                            \
    dst[mt3] = *(const bf16x8*)(                                               \
        w4f + (size_t)((mt3 * 16 + (chunkprev) * 2 + (ks3)) * 64 + lane) * 8);

#define L3_PART(w4q, hq)                                                       \
  __builtin_amdgcn_s_setprio(1);                                               \
  _Pragma("unroll")                                                            \
  for (int mt3 = 0; mt3 < 3; ++mt3)                                            \
    _Pragma("unroll")                                                          \
    for (int rg = 0; rg < 4; ++rg)                                             \
      accO[mt3][rg] = __builtin_amdgcn_mfma_f32_16x16x32_bf16(                 \
          w4q[mt3], hq[rg], accO[mt3][rg], 0, 0, 0);                           \
  __builtin_amdgcn_s_setprio(0);

// 128 threads = 2 waves; each wave privately owns 64 rows (4 N-groups of 16).
// All LDS traffic is wave-private (DS ops complete in order per wave) -> the
// kernel contains NO __syncthreads / s_barrier at all.
__global__ __launch_bounds__(128, 2) void dqn_fused(
    const float* __restrict__ x,
    const unsigned short* __restrict__ wf,
    const float* __restrict__ b1,
    const float* __restrict__ b2,
    const float* __restrict__ b4,
    float* __restrict__ out) {
  __shared__ __align__(16) unsigned short sBuf[2 * 64 * SROW];  // 34816 B -> 4 blocks/CU

  const int tid  = threadIdx.x;
  const int lane = tid & 63;
  const int wave = tid >> 6;                     // 0 or 1
  const int quad = lane >> 4;
  const int l16  = lane & 15;
  const int row0 = blockIdx.x << 7;              // 128 rows per block
  const int lr0  = wave * 64;
  unsigned short* su = sBuf + wave * (64 * SROW);  // wave-private

  const unsigned short* w2f = wf + NW1F;
  const unsigned short* w4f = wf + NW1F + NW2F;
  const unsigned short* w2p = w2f + lane * 8;    // frag f lives at w2p + f*512

  // software-pipeline prologue: W2 frag-quad 0 (chunk0, mtl0) into parity buffer 0;
  // its latency overlaps input staging + the whole L1 GEMM.
  bf16x8 W[2][4];
#pragma unroll
  for (int k = 0; k < 4; ++k) W[0][k] = *(const bf16x8*)(w2p + (size_t)k * 512);

  // ---- stage 1: one-hot input rows in LDS (bf16), K padded 36->64; 1 row/lane ----
  {
    const float* xr = x + (size_t)(row0 + lr0 + lane) * 15;
    unsigned short* dst = su + lane * SROW;
    bf16x8 z = {0, 0, 0, 0, 0, 0, 0, 0};
#pragma unroll
    for (int c = 8; c < 64; c += 8) *(bf16x8*)(dst + c) = z;   // zero cols 8..63
    u32 p[4];
#pragma unroll
    for (int i = 0; i < 4; ++i) p[i] = cvtpk(xr[2 * i], xr[2 * i + 1]);
    *(bf16x8*)dst = *(bf16x8*)p;                 // keep cols 0..7
    *(u32*)(dst + 8) = cvtpk(xr[8], xr[9]);      // keep cols 8..9
    dst[10] = f2bf(xr[10]);                      // keep col 10
    int hold = (int)xr[11]; hold = hold < 0 ? 0 : (hold > 3 ? 3 : hold);
    dst[11 + hold] = 0x3F80;                     // bf16 1.0
#pragma unroll
    for (int t = 0; t < 3; ++t) {
      int nx = (int)xr[12 + t] - 1; nx = nx < 0 ? 0 : (nx > 6 ? 6 : nx);
      dst[15 + t * 7 + nx] = 0x3F80;
    }
  }

  const f32x4 vzero = {0.f, 0.f, 0.f, 0.f};

  // ---- stage 2: h1^T = relu(W1^T @ inp^T + b1), two mt-halves; af1 frags to regs.
  bf16x8 ib[4][2];
#pragma unroll
  for (int rg = 0; rg < 4; ++rg)
#pragma unroll
    for (int ks = 0; ks < 2; ++ks)
      ib[rg][ks] = *(const bf16x8*)(su + (rg * 16 + l16) * SROW + ks * 32 + quad * 8);

  bf16x8 af1[4][4];   // [rg][ks_out]: h1 B-frags, filled per half
#pragma unroll
  for (int half = 0; half < 2; ++half) {
    // hoist this half's 8 W1 frags before the MFMA burst (latency overlap)
    bf16x8 wa[4][2];
#pragma unroll
    for (int mtl = 0; mtl < 4; ++mtl)
#pragma unroll
      for (int ks = 0; ks < 2; ++ks)
        wa[mtl][ks] = *(const bf16x8*)(
            wf + (size_t)(((half * 4 + mtl) * 2 + ks) * 64 + lane) * 8);

    // bias carried in the MFMA C operand
    f32x4 acc1[4][4];   // [mtl][rg]
#pragma unroll
    for (int mtl = 0; mtl < 4; ++mtl) {
      f32x4 bias = *(const f32x4*)(b1 + (half * 4 + mtl) * 16 + quad * 4);
#pragma unroll
      for (int rg = 0; rg < 4; ++rg) acc1[mtl][rg] = bias;
    }

    __builtin_amdgcn_s_setprio(1);
#pragma unroll
    for (int mtl = 0; mtl < 4; ++mtl)
#pragma unroll
      for (int ks = 0; ks < 2; ++ks)
#pragma unroll
        for (int rg = 0; rg < 4; ++rg)
          acc1[mtl][rg] = __builtin_amdgcn_mfma_f32_16x16x32_bf16(wa[mtl][ks], ib[rg][ks], acc1[mtl][rg], 0, 0, 0);
    __builtin_amdgcn_s_setprio(0);

#pragma unroll
    for (int mtl = 0; mtl < 4; ++mtl) {
#pragma unroll
      for (int rg = 0; rg < 4; ++rg) {
        float v0 = fmaxf(acc1[mtl][rg][0], 0.f);
        float v1 = fmaxf(acc1[mtl][rg][1], 0.f);
        float v2 = fmaxf(acc1[mtl][rg][2], 0.f);
        float v3 = fmaxf(acc1[mtl][rg][3], 0.f);
        uint2 pk = {cvtpk(v0, v1), cvtpk(v2, v3)};
        *(uint2*)(su + (rg * 16 + l16) * SROW + mtl * 16 + quad * 4) = pk;
      }
    }
#pragma unroll
    for (int rg = 0; rg < 4; ++rg)
#pragma unroll
      for (int ksl = 0; ksl < 2; ++ksl)
        af1[rg][half * 2 + ksl] =
            *(const bf16x8*)(su + (rg * 16 + l16) * SROW + ksl * 32 + quad * 8);
  }

  f32x4 accO[3][4];
#pragma unroll
  for (int mt = 0; mt < 3; ++mt)
#pragma unroll
    for (int rg = 0; rg < 4; ++rg) accO[mt][rg] = vzero;

  // ---- stage 3: chunk-level software pipeline, no barriers ----
  // chunk c's W2 bursts fill h2 buffer (c&1); chunk c-1's L3 partial is
  // interleaved into c's mtl loop reading buffer ((c-1)&1).
  {
    // chunk 0: fill buf0, no L3 yet
    f32x4 bias2[4];
#pragma unroll
    for (int mtl = 0; mtl < 4; ++mtl)
      bias2[mtl] = *(const f32x4*)(b2 + mtl * 16 + quad * 4);
    MTL_STEP(0, 0, 0)
    MTL_STEP(0, 1, 0)
    MTL_STEP(0, 2, 0)
    MTL_STEP(0, 3, 0)
  }
  for (int chunk = 1; chunk < 8; ++chunk) {
    const int hb  = (chunk & 1) * 72;   // current h2 buffer column offset
    const int hbp = 72 - hb;            // previous chunk's buffer
    f32x4 bias2[4];
#pragma unroll
    for (int mtl = 0; mtl < 4; ++mtl)
      bias2[mtl] = *(const f32x4*)(b2 + chunk * 64 + mtl * 16 + quad * 4);

    bf16x8 w4a[3];
    W4_LOAD(w4a, chunk - 1, 0)          // global loads ~2 mtl-steps ahead of use
    MTL_STEP(chunk, 0, hb)
    bf16x8 h0[4];
    H_READ(h0, hbp, 0)                  // ds_reads one mtl-step ahead of use
    MTL_STEP(chunk, 1, hb)
    L3_PART(w4a, h0)
    bf16x8 w4b[3];
    W4_LOAD(w4b, chunk - 1, 1)
    MTL_STEP(chunk, 2, hb)
    bf16x8 h1v[4];
    H_READ(h1v, hbp, 1)
    MTL_STEP(chunk, 3, hb)
    L3_PART(w4b, h1v)
  }
  {
    // pipeline tail: L3 partial of chunk 7 (buffer offset 72)
    bf16x8 w4a[3];
    W4_LOAD(w4a, 7, 0)
    bf16x8 h0[4];
    H_READ(h0, 72, 0)
    L3_PART(w4a, h0)
    bf16x8 w4b[3];
    W4_LOAD(w4b, 7, 1)
    bf16x8 h1v[4];
    H_READ(h1v, 72, 1)
    L3_PART(w4b, h1v)
  }

  // ---- epilogue: +b4, float4 stores (lane holds 4 consecutive out-cols) ----
#pragma unroll
  for (int mt3 = 0; mt3 < 3; ++mt3) {
    int colbase = mt3 * 16 + quad * 4;
    if (colbase < 40) {                      // drops pad cols 40..47 (b4 OOB-safe)
      f32x4 bias = *(const f32x4*)(b4 + colbase);
#pragma unroll
      for (int rg = 0; rg < 4; ++rg) {
        f32x4 v = accO[mt3][rg] + bias;
        size_t row = (size_t)(row0 + lr0 + rg * 16 + l16);
        *(f32x4*)(out + row * 40 + colbase) = v;
      }
    }
  }
}

extern "C" void kernel_launch(void* const* d_in, const int* in_sizes, int n_in,
                              void* d_out, int out_size, void* d_ws, size_t ws_size,
                              hipStream_t stream) {
  const float* x  = (const float*)d_in[0];
  const float* W1 = (const float*)d_in[1];
  const float* b1 = (const float*)d_in[2];
  const float* W2 = (const float*)d_in[3];
  const float* b2 = (const float*)d_in[4];
  const float* W4 = (const float*)d_in[5];
  const float* b4 = (const float*)d_in[6];
  float* out = (float*)d_out;
  unsigned short* wf = (unsigned short*)d_ws;   // 192 KB of ws

  int B = in_sizes[0] / 15;

  hipLaunchKernelGGL(pack_weights, dim3((PACK_THREADS + 255) / 256), dim3(256), 0, stream,
                     W1, W2, W4, wf);
  hipLaunchKernelGGL(dqn_fused, dim3(B / 128), dim3(128), 0, stream,
                     x, wf, b1, b2, b4, out);
}